// Round 1
// baseline (259.945 us; speedup 1.0000x reference)
//
#include <hip/hip_runtime.h>

#define NN 16384      // nodes
#define EE 262144     // edges
#define HH 128        // hidden
#define GG 256        // graphs
#define NPG 64        // nodes per graph

// ---------------- embedding: h = class_emb[x0] + neigh_emb[x1] ----------------
__global__ __launch_bounds__(256) void k_embed(const int* __restrict__ x,
    const float* __restrict__ ce, const float* __restrict__ ne, float* __restrict__ h) {
  int t = blockIdx.x * 256 + threadIdx.x;   // one float4 per thread, N*32 total
  int n = t >> 5, q = t & 31;
  int c0 = x[2 * n], c1 = x[2 * n + 1];
  float4 a = ((const float4*)ce)[c0 * 32 + q];
  float4 b = ((const float4*)ne)[c1 * 32 + q];
  float4 o; o.x = a.x + b.x; o.y = a.y + b.y; o.z = a.z + b.z; o.w = a.w + b.w;
  ((float4*)h)[t] = o;
}

// ---------------- degree histogram over dst ----------------
__global__ __launch_bounds__(256) void k_deg(const int* __restrict__ ei, int* __restrict__ deg) {
  int e = blockIdx.x * 256 + threadIdx.x;
  atomicAdd(&deg[ei[EE + e]], 1);
}

// ---------------- single-block exclusive scan -> row_ptr, cursor, dinv ----------------
__global__ __launch_bounds__(1024) void k_scan(const int* __restrict__ deg, float* __restrict__ dinv,
    int* __restrict__ row_ptr, int* __restrict__ cursor) {
  __shared__ int part[1024];
  int t = threadIdx.x;
  int base = t * 16;
  int local[16]; int s = 0;
#pragma unroll
  for (int i = 0; i < 16; ++i) { local[i] = s; s += deg[base + i]; }
  part[t] = s;
  __syncthreads();
  for (int o = 1; o < 1024; o <<= 1) {
    int v = part[t];
    int add = (t >= o) ? part[t - o] : 0;
    __syncthreads();
    part[t] = v + add;
    __syncthreads();
  }
  int pre = (t > 0) ? part[t - 1] : 0;
#pragma unroll
  for (int i = 0; i < 16; ++i) {
    int rp = pre + local[i];
    row_ptr[base + i] = rp;
    cursor[base + i] = rp;
    dinv[base + i] = rsqrtf((float)(deg[base + i] + 1));   // +1 self loop
  }
  if (t == 1023) row_ptr[NN] = part[1023];
}

// ---------------- CSR fill (col = src, grouped by dst) ----------------
__global__ __launch_bounds__(256) void k_fill(const int* __restrict__ ei,
    int* __restrict__ cursor, int* __restrict__ col) {
  int e = blockIdx.x * 256 + threadIdx.x;
  int d = ei[EE + e];
  int p = atomicAdd(&cursor[d], 1);
  col[p] = ei[e];
}

// ---------------- fp32 GEMM: C[16384x128] = A[16384x128] @ W[128x128] ----------------
// block = 256 threads, 64 rows per block; W (64KB) + padded A-tile (33KB) in LDS.
__global__ __launch_bounds__(256) void k_gemm(const float* __restrict__ A,
    const float* __restrict__ W, float* __restrict__ C) {
  __shared__ float Wl[128 * 128];
  __shared__ float Al[64 * 132];     // +4 pad breaks bank aliasing on row reads
  int tid = threadIdx.x;
  int rbase = blockIdx.x * 64;
  {
    const float4* W4 = (const float4*)W;
    float4* Wl4 = (float4*)Wl;
#pragma unroll
    for (int i = 0; i < 16; ++i) Wl4[tid + 256 * i] = W4[tid + 256 * i];
  }
  {
    const float4* A4 = (const float4*)(A + rbase * HH);
#pragma unroll
    for (int i = 0; i < 8; ++i) {
      int idx = tid + 256 * i;           // float4 index; row = idx/32, q = idx%32
      int r = idx >> 5, q = idx & 31;
      float4 v = A4[idx];
      *(float4*)&Al[r * 132 + q * 4] = v;
    }
  }
  __syncthreads();
  int cg = (tid & 31) * 4;               // 4 consecutive cols
  int r0 = (tid >> 5) * 8;               // 8 rows
  float acc[8][4];
#pragma unroll
  for (int i = 0; i < 8; ++i)
#pragma unroll
    for (int j = 0; j < 4; ++j) acc[i][j] = 0.f;
  for (int k = 0; k < 128; ++k) {
    float4 w = *(const float4*)&Wl[k * 128 + cg];
    float a[8];
#pragma unroll
    for (int i = 0; i < 8; ++i) a[i] = Al[(r0 + i) * 132 + k];
#pragma unroll
    for (int i = 0; i < 8; ++i) {
      acc[i][0] += a[i] * w.x; acc[i][1] += a[i] * w.y;
      acc[i][2] += a[i] * w.z; acc[i][3] += a[i] * w.w;
    }
  }
#pragma unroll
  for (int i = 0; i < 8; ++i) {
    float4 o; o.x = acc[i][0]; o.y = acc[i][1]; o.z = acc[i][2]; o.w = acc[i][3];
    *(float4*)&C[(rbase + r0 + i) * HH + cg] = o;
  }
}

// ---------------- fused aggregate + bias + relu + residual + layernorm ----------------
// wave per node, float2 per lane (128 elems / 64 lanes)
__global__ __launch_bounds__(256) void k_agg(const float* __restrict__ hw, float* __restrict__ h,
    const int* __restrict__ row_ptr, const int* __restrict__ col, const float* __restrict__ dinv,
    const float* __restrict__ bias, const float* __restrict__ g, const float* __restrict__ bln) {
  int wv = threadIdx.x >> 6, lane = threadIdx.x & 63;
  int n = blockIdx.x * 4 + wv;
  const float2* hw2 = (const float2*)hw;
  float2* h2 = (float2*)h;
  float dn = dinv[n];
  float2 sv = hw2[n * 64 + lane];
  float a0x = sv.x * dn * dn, a0y = sv.y * dn * dn;   // self loop
  float a1x = 0.f, a1y = 0.f, a2x = 0.f, a2y = 0.f, a3x = 0.f, a3y = 0.f;
  int e = row_ptr[n], end = row_ptr[n + 1];
  for (; e + 4 <= end; e += 4) {
    int s0 = col[e], s1 = col[e + 1], s2 = col[e + 2], s3 = col[e + 3];
    float n0 = dinv[s0] * dn, n1 = dinv[s1] * dn, n2 = dinv[s2] * dn, n3 = dinv[s3] * dn;
    float2 v0 = hw2[s0 * 64 + lane];
    float2 v1 = hw2[s1 * 64 + lane];
    float2 v2 = hw2[s2 * 64 + lane];
    float2 v3 = hw2[s3 * 64 + lane];
    a0x += v0.x * n0; a0y += v0.y * n0;
    a1x += v1.x * n1; a1y += v1.y * n1;
    a2x += v2.x * n2; a2y += v2.y * n2;
    a3x += v3.x * n3; a3y += v3.y * n3;
  }
  for (; e < end; ++e) {
    int s0 = col[e]; float n0 = dinv[s0] * dn;
    float2 v0 = hw2[s0 * 64 + lane];
    a0x += v0.x * n0; a0y += v0.y * n0;
  }
  float accx = (a0x + a1x) + (a2x + a3x);
  float accy = (a0y + a1y) + (a2y + a3y);
  // epilogue: +bias, relu, +h, layernorm
  int d = lane * 2;
  float2 b2 = *(const float2*)&bias[d];
  float hnx = fmaxf(accx + b2.x, 0.f), hny = fmaxf(accy + b2.y, 0.f);
  float2 hv = h2[n * 64 + lane];
  float rx = hv.x + hnx, ry = hv.y + hny;
  float s1 = rx + ry, s2 = rx * rx + ry * ry;
#pragma unroll
  for (int o = 1; o < 64; o <<= 1) { s1 += __shfl_xor(s1, o); s2 += __shfl_xor(s2, o); }
  float mu = s1 * (1.f / 128.f);
  float var = s2 * (1.f / 128.f) - mu * mu;
  float rstd = rsqrtf(var + 1e-5f);
  float2 gg = *(const float2*)&g[d];
  float2 bb = *(const float2*)&bln[d];
  float2 o2;
  o2.x = (rx - mu) * rstd * gg.x + bb.x;
  o2.y = (ry - mu) * rstd * gg.y + bb.y;
  h2[n * 64 + lane] = o2;
}

// ---------------- last layer: fully-adjacent conv (deg==65 uniform) + fused epilogue ----------------
__global__ __launch_bounds__(256) void k_fa(const float* __restrict__ hw, float* __restrict__ h,
    const float* __restrict__ bias, const float* __restrict__ g, const float* __restrict__ bln) {
  __shared__ float tmp[256];
  __shared__ float gsum[128];
  int gph = blockIdx.x;
  int tid = threadIdx.x;
  int d = tid & 127, half = tid >> 7;
  const float* hwbase = hw + gph * NPG * HH;
  float s = 0.f;
#pragma unroll
  for (int r = 0; r < 32; ++r) s += hwbase[(half * 32 + r) * HH + d];
  tmp[tid] = s;
  __syncthreads();
  if (tid < 128) gsum[tid] = tmp[tid] + tmp[tid + 128];
  __syncthreads();
  int wv = tid >> 6, lane = tid & 63;
  const float inv65 = 1.0f / 65.0f;
  float2 gs = *(const float2*)&gsum[lane * 2];
  float2 b2 = *(const float2*)&bias[lane * 2];
  float2 gg = *(const float2*)&g[lane * 2];
  float2 bb = *(const float2*)&bln[lane * 2];
  for (int ni = wv; ni < NPG; ni += 4) {
    int n = gph * NPG + ni;
    float2 hwv = ((const float2*)hw)[n * 64 + lane];
    float ax = fmaxf((gs.x + hwv.x) * inv65 + b2.x, 0.f);
    float ay = fmaxf((gs.y + hwv.y) * inv65 + b2.y, 0.f);
    float2 hv = ((float2*)h)[n * 64 + lane];
    float rx = hv.x + ax, ry = hv.y + ay;
    float s1 = rx + ry, s2 = rx * rx + ry * ry;
#pragma unroll
    for (int o = 1; o < 64; o <<= 1) { s1 += __shfl_xor(s1, o); s2 += __shfl_xor(s2, o); }
    float mu = s1 * (1.f / 128.f);
    float var = s2 * (1.f / 128.f) - mu * mu;
    float rstd = rsqrtf(var + 1e-5f);
    float2 o2;
    o2.x = (rx - mu) * rstd * gg.x + bb.x;
    o2.y = (ry - mu) * rstd * gg.y + bb.y;
    ((float2*)h)[n * 64 + lane] = o2;
  }
}

// ---------------- readout: out[g] = h[g*64] @ out_W + out_b ----------------
__global__ __launch_bounds__(256) void k_out(const float* __restrict__ h,
    const float* __restrict__ W, const float* __restrict__ b, float* __restrict__ out) {
  int wv = threadIdx.x >> 6, lane = threadIdx.x & 63;
  int gph = blockIdx.x * 4 + wv;
  int c = lane & 31, half = lane >> 5;
  const float* hr = h + gph * NPG * HH;   // root = node 0 of graph
  float acc = 0.f;
  for (int k = half * 64; k < half * 64 + 64; ++k) acc += hr[k] * W[k * 32 + c];
  acc += __shfl_xor(acc, 32);
  if (half == 0) out[gph * 32 + c] = acc + b[c];
}

extern "C" void kernel_launch(void* const* d_in, const int* in_sizes, int n_in,
                              void* d_out, int out_size, void* d_ws, size_t ws_size,
                              hipStream_t stream) {
  const int*   x  = (const int*)d_in[0];
  const int*   ei = (const int*)d_in[1];
  const float* ce = (const float*)d_in[3];
  const float* ne = (const float*)d_in[4];
  const float* Ws = (const float*)d_in[5];
  const float* bs = (const float*)d_in[6];
  const float* lg = (const float*)d_in[7];
  const float* lb = (const float*)d_in[8];
  const float* oW = (const float*)d_in[9];
  const float* ob = (const float*)d_in[10];
  float* out = (float*)d_out;

  float* h      = (float*)d_ws;
  float* hw     = h + NN * HH;
  int*   deg    = (int*)(hw + NN * HH);
  float* dinv   = (float*)(deg + NN);
  int*   row_ptr= (int*)(dinv + NN);
  int*   cursor = row_ptr + NN + 64;
  int*   col    = cursor + NN;

  hipMemsetAsync(deg, 0, NN * sizeof(int), stream);
  k_embed<<<NN * 32 / 256, 256, 0, stream>>>(x, ce, ne, h);
  k_deg<<<EE / 256, 256, 0, stream>>>(ei, deg);
  k_scan<<<1, 1024, 0, stream>>>(deg, dinv, row_ptr, cursor);
  k_fill<<<EE / 256, 256, 0, stream>>>(ei, cursor, col);
  for (int l = 0; l < 3; ++l) {
    k_gemm<<<NN / 64, 256, 0, stream>>>(h, Ws + l * HH * HH, hw);
    k_agg<<<NN / 4, 256, 0, stream>>>(hw, h, row_ptr, col, dinv,
                                      bs + l * HH, lg + l * HH, lb + l * HH);
  }
  k_gemm<<<NN / 64, 256, 0, stream>>>(h, Ws + 3 * HH * HH, hw);
  k_fa<<<GG, 256, 0, stream>>>(hw, h, bs + 3 * HH, lg + 3 * HH, lb + 3 * HH);
  k_out<<<GG / 4, 256, 0, stream>>>(h, oW, ob, out);
}

// Round 2
// 243.550 us; speedup vs baseline: 1.0673x; 1.0673x over previous
//
#include <hip/hip_runtime.h>

#define NN 16384      // nodes
#define EE 262144     // edges
#define HH 128        // hidden
#define GG 256        // graphs
#define NPG 64        // nodes per graph

// ---------------- embedding + degree histogram fused ----------------
__global__ __launch_bounds__(256) void k_prep(const int* __restrict__ x,
    const float* __restrict__ ce, const float* __restrict__ ne, float* __restrict__ h,
    const int* __restrict__ ei, int* __restrict__ deg) {
  int t = blockIdx.x * 256 + threadIdx.x;   // one float4 per thread, N*32 total
  int n = t >> 5, q = t & 31;
  int c0 = x[2 * n], c1 = x[2 * n + 1];
  float4 a = ((const float4*)ce)[c0 * 32 + q];
  float4 b = ((const float4*)ne)[c1 * 32 + q];
  float4 o; o.x = a.x + b.x; o.y = a.y + b.y; o.z = a.z + b.z; o.w = a.w + b.w;
  ((float4*)h)[t] = o;
  if (t < EE) atomicAdd(&deg[ei[EE + t]], 1);
}

// ---------------- single-block exclusive scan -> row_ptr, cursor, dinv ----------------
__global__ __launch_bounds__(1024) void k_scan(const int* __restrict__ deg, float* __restrict__ dinv,
    int* __restrict__ row_ptr, int* __restrict__ cursor) {
  __shared__ int part[1024];
  int t = threadIdx.x;
  int base = t * 16;
  int local[16]; int s = 0;
#pragma unroll
  for (int i = 0; i < 16; ++i) { local[i] = s; s += deg[base + i]; }
  part[t] = s;
  __syncthreads();
  for (int o = 1; o < 1024; o <<= 1) {
    int v = part[t];
    int add = (t >= o) ? part[t - o] : 0;
    __syncthreads();
    part[t] = v + add;
    __syncthreads();
  }
  int pre = (t > 0) ? part[t - 1] : 0;
#pragma unroll
  for (int i = 0; i < 16; ++i) {
    int rp = pre + local[i];
    row_ptr[base + i] = rp;
    cursor[base + i] = rp;
    dinv[base + i] = rsqrtf((float)(deg[base + i] + 1));   // +1 self loop
  }
  if (t == 1023) row_ptr[NN] = part[1023];
}

// ---------------- CSR fill (col = src, grouped by dst) ----------------
__global__ __launch_bounds__(256) void k_fill(const int* __restrict__ ei,
    int* __restrict__ cursor, int* __restrict__ col) {
  int e = blockIdx.x * 256 + threadIdx.x;
  int d = ei[EE + e];
  int p = atomicAdd(&cursor[d], 1);
  col[p] = ei[e];
}

// ---------------- fp32 GEMM: C[16384x128] = A[16384x128] @ W[128x128] ----------------
// 512 threads, 64 rows/block, K chunked by 32. LDS 25.6KB -> 2 waves/SIMD.
// All LDS reads are b128; thread tile 4x4; FMA:LDS = 8:1.
__global__ __launch_bounds__(512) void k_gemm(const float* __restrict__ A,
    const float* __restrict__ W, float* __restrict__ C) {
  __shared__ __align__(16) float Al[64][36];   // stride 144B (16B-aligned, staggered banks)
  __shared__ __align__(16) float Wl[32][128];
  int tid = threadIdx.x;
  int rbase = blockIdx.x * 64;
  int cg = (tid & 31) * 4;        // col0 of 4 cols
  int rg = (tid >> 5) * 4;        // row0 of 4 rows
  float acc[4][4];
#pragma unroll
  for (int i = 0; i < 4; ++i)
#pragma unroll
    for (int j = 0; j < 4; ++j) acc[i][j] = 0.f;

  int sr = tid >> 3, sq = tid & 7;            // A-stage: 64 rows x 8 float4
  for (int kc = 0; kc < 4; ++kc) {
    int k0 = kc * 32;
    float4 va = *(const float4*)&A[(rbase + sr) * HH + k0 + sq * 4];
    *(float4*)&Al[sr][sq * 4] = va;
#pragma unroll
    for (int i = 0; i < 2; ++i) {
      int f = tid + 512 * i;
      int kk = f >> 5, q = f & 31;
      float4 vw = *(const float4*)&W[(k0 + kk) * HH + q * 4];
      *(float4*)&Wl[kk][q * 4] = vw;
    }
    __syncthreads();
#pragma unroll
    for (int kk = 0; kk < 32; kk += 4) {
      float av[4][4], wv_[4][4];
#pragma unroll
      for (int i = 0; i < 4; ++i) *(float4*)av[i] = *(const float4*)&Al[rg + i][kk];
#pragma unroll
      for (int j = 0; j < 4; ++j) *(float4*)wv_[j] = *(const float4*)&Wl[kk + j][cg];
#pragma unroll
      for (int j = 0; j < 4; ++j)
#pragma unroll
        for (int i = 0; i < 4; ++i)
#pragma unroll
          for (int c = 0; c < 4; ++c) acc[i][c] = fmaf(av[i][j], wv_[j][c], acc[i][c]);
    }
    __syncthreads();
  }
#pragma unroll
  for (int i = 0; i < 4; ++i) {
    float4 o; o.x = acc[i][0]; o.y = acc[i][1]; o.z = acc[i][2]; o.w = acc[i][3];
    *(float4*)&C[(rbase + rg + i) * HH + cg] = o;
  }
}

// ---------------- fused aggregate + bias + relu + residual + layernorm ----------------
// wave per node; 64 edges' col/dinv batch-loaded per lane, broadcast via shfl;
// 4 gathers in flight per unrolled step.
__global__ __launch_bounds__(256) void k_agg(const float* __restrict__ hw, float* __restrict__ h,
    const int* __restrict__ row_ptr, const int* __restrict__ col, const float* __restrict__ dinv,
    const float* __restrict__ bias, const float* __restrict__ g, const float* __restrict__ bln) {
  int wv = threadIdx.x >> 6, lane = threadIdx.x & 63;
  int n = blockIdx.x * 4 + wv;
  const float2* hw2 = (const float2*)hw;
  float2* h2 = (float2*)h;
  float dn = dinv[n];
  float2 sv = hw2[n * 64 + lane];
  float a0x = sv.x * dn * dn, a0y = sv.y * dn * dn;   // self loop
  float a1x = 0.f, a1y = 0.f, a2x = 0.f, a2y = 0.f, a3x = 0.f, a3y = 0.f;
  int e0 = row_ptr[n], end = row_ptr[n + 1];
  for (int base = e0; base < end; base += 64) {
    int idx = base + lane;
    int cl = 0; float dv = 0.f;
    if (idx < end) { cl = col[idx]; dv = dinv[cl]; }
    int m = min(64, end - base);
    int j = 0;
    for (; j + 4 <= m; j += 4) {
      int s0 = __shfl(cl, j),     s1 = __shfl(cl, j + 1);
      int s2 = __shfl(cl, j + 2), s3 = __shfl(cl, j + 3);
      float n0 = __shfl(dv, j) * dn,     n1 = __shfl(dv, j + 1) * dn;
      float n2 = __shfl(dv, j + 2) * dn, n3 = __shfl(dv, j + 3) * dn;
      float2 v0 = hw2[s0 * 64 + lane];
      float2 v1 = hw2[s1 * 64 + lane];
      float2 v2 = hw2[s2 * 64 + lane];
      float2 v3 = hw2[s3 * 64 + lane];
      a0x = fmaf(v0.x, n0, a0x); a0y = fmaf(v0.y, n0, a0y);
      a1x = fmaf(v1.x, n1, a1x); a1y = fmaf(v1.y, n1, a1y);
      a2x = fmaf(v2.x, n2, a2x); a2y = fmaf(v2.y, n2, a2y);
      a3x = fmaf(v3.x, n3, a3x); a3y = fmaf(v3.y, n3, a3y);
    }
    for (; j < m; ++j) {
      int s0 = __shfl(cl, j); float n0 = __shfl(dv, j) * dn;
      float2 v0 = hw2[s0 * 64 + lane];
      a0x = fmaf(v0.x, n0, a0x); a0y = fmaf(v0.y, n0, a0y);
    }
  }
  float accx = (a0x + a1x) + (a2x + a3x);
  float accy = (a0y + a1y) + (a2y + a3y);
  int d = lane * 2;
  float2 b2 = *(const float2*)&bias[d];
  float hnx = fmaxf(accx + b2.x, 0.f), hny = fmaxf(accy + b2.y, 0.f);
  float2 hv = h2[n * 64 + lane];
  float rx = hv.x + hnx, ry = hv.y + hny;
  float s1 = rx + ry, s2 = rx * rx + ry * ry;
#pragma unroll
  for (int o = 1; o < 64; o <<= 1) { s1 += __shfl_xor(s1, o); s2 += __shfl_xor(s2, o); }
  float mu = s1 * (1.f / 128.f);
  float var = s2 * (1.f / 128.f) - mu * mu;
  float rstd = rsqrtf(var + 1e-5f);
  float2 gg = *(const float2*)&g[d];
  float2 bb = *(const float2*)&bln[d];
  float2 o2;
  o2.x = (rx - mu) * rstd * gg.x + bb.x;
  o2.y = (ry - mu) * rstd * gg.y + bb.y;
  h2[n * 64 + lane] = o2;
}

// ---------------- last layer: FA conv (deg==65) + epilogue + root readout fused ----------------
__global__ __launch_bounds__(256) void k_fa_out(const float* __restrict__ hw, float* __restrict__ h,
    const float* __restrict__ bias, const float* __restrict__ g, const float* __restrict__ bln,
    const float* __restrict__ oW, const float* __restrict__ ob, float* __restrict__ out) {
  __shared__ float tmp[256];
  __shared__ float gsum[128];
  __shared__ float part[8][32];
  int gph = blockIdx.x;
  int tid = threadIdx.x;
  int d = tid & 127, half = tid >> 7;
  const float* hwbase = hw + gph * NPG * HH;
  float s = 0.f;
#pragma unroll
  for (int r = 0; r < 32; ++r) s += hwbase[(half * 32 + r) * HH + d];
  tmp[tid] = s;
  __syncthreads();
  if (tid < 128) gsum[tid] = tmp[tid] + tmp[tid + 128];
  __syncthreads();
  int wv = tid >> 6, lane = tid & 63;
  const float inv65 = 1.0f / 65.0f;
  float2 gs = *(const float2*)&gsum[lane * 2];
  float2 b2 = *(const float2*)&bias[lane * 2];
  float2 gg = *(const float2*)&g[lane * 2];
  float2 bb = *(const float2*)&bln[lane * 2];
  __syncthreads();   // gsum/params in regs; tmp free for reuse below
  for (int ni = wv; ni < NPG; ni += 4) {
    int n = gph * NPG + ni;
    float2 hwv = ((const float2*)hw)[n * 64 + lane];
    float ax = fmaxf((gs.x + hwv.x) * inv65 + b2.x, 0.f);
    float ay = fmaxf((gs.y + hwv.y) * inv65 + b2.y, 0.f);
    float2 hv = ((float2*)h)[n * 64 + lane];
    float rx = hv.x + ax, ry = hv.y + ay;
    float s1 = rx + ry, s2 = rx * rx + ry * ry;
#pragma unroll
    for (int o = 1; o < 64; o <<= 1) { s1 += __shfl_xor(s1, o); s2 += __shfl_xor(s2, o); }
    float mu = s1 * (1.f / 128.f);
    float var = s2 * (1.f / 128.f) - mu * mu;
    float rstd = rsqrtf(var + 1e-5f);
    float2 o2;
    o2.x = (rx - mu) * rstd * gg.x + bb.x;
    o2.y = (ry - mu) * rstd * gg.y + bb.y;
    ((float2*)h)[n * 64 + lane] = o2;
    if (ni == 0) { tmp[lane * 2] = o2.x; tmp[lane * 2 + 1] = o2.y; }  // root row
  }
  __syncthreads();
  // readout: out[gph] = root @ oW + ob   (oW row-major [128][32])
  int c = tid & 31, seg = tid >> 5;
  float p = 0.f;
#pragma unroll
  for (int k = 0; k < 16; ++k) p = fmaf(tmp[seg * 16 + k], oW[(seg * 16 + k) * 32 + c], p);
  part[seg][c] = p;
  __syncthreads();
  if (tid < 32) {
    float so = ob[tid];
#pragma unroll
    for (int i = 0; i < 8; ++i) so += part[i][tid];
    out[gph * 32 + tid] = so;
  }
}

extern "C" void kernel_launch(void* const* d_in, const int* in_sizes, int n_in,
                              void* d_out, int out_size, void* d_ws, size_t ws_size,
                              hipStream_t stream) {
  const int*   x  = (const int*)d_in[0];
  const int*   ei = (const int*)d_in[1];
  const float* ce = (const float*)d_in[3];
  const float* ne = (const float*)d_in[4];
  const float* Ws = (const float*)d_in[5];
  const float* bs = (const float*)d_in[6];
  const float* lg = (const float*)d_in[7];
  const float* lb = (const float*)d_in[8];
  const float* oW = (const float*)d_in[9];
  const float* ob = (const float*)d_in[10];
  float* out = (float*)d_out;

  float* h      = (float*)d_ws;
  float* hw     = h + NN * HH;
  int*   deg    = (int*)(hw + NN * HH);
  float* dinv   = (float*)(deg + NN);
  int*   row_ptr= (int*)(dinv + NN);
  int*   cursor = row_ptr + NN + 64;
  int*   col    = cursor + NN;

  hipMemsetAsync(deg, 0, NN * sizeof(int), stream);
  k_prep<<<NN * 32 / 256, 256, 0, stream>>>(x, ce, ne, h, ei, deg);
  k_scan<<<1, 1024, 0, stream>>>(deg, dinv, row_ptr, cursor);
  k_fill<<<EE / 256, 256, 0, stream>>>(ei, cursor, col);
  for (int l = 0; l < 3; ++l) {
    k_gemm<<<NN / 64, 512, 0, stream>>>(h, Ws + l * HH * HH, hw);
    k_agg<<<NN / 4, 256, 0, stream>>>(hw, h, row_ptr, col, dinv,
                                      bs + l * HH, lg + l * HH, lb + l * HH);
  }
  k_gemm<<<NN / 64, 512, 0, stream>>>(h, Ws + 3 * HH * HH, hw);
  k_fa_out<<<GG, 256, 0, stream>>>(hw, h, bs + 3 * HH, lg + 3 * HH, lb + 3 * HH, oW, ob, out);
}